// Round 1
// baseline (603.501 us; speedup 1.0000x reference)
//
#include <hip/hip_runtime.h>
#include <cstdint>
#include <cstddef>

// ConfusionDropout: B=16384 rows; D=4096 channels; C=1000 classes; drop top 25% (1024).
constexpr int Dn    = 4096;
constexpr int Cn    = 1000;
constexpr int NDROP = 1024;   // Dn * 0.25
constexpr int TPB   = 256;    // 4 waves per block, 16 channels per thread

// Monotonic (value, smaller-index-wins) packing for top-k with lax.top_k tie-break.
__device__ __forceinline__ unsigned long long pack_pv(float v, unsigned idx) {
  unsigned b = __float_as_uint(v);
  unsigned u = b ^ ((b & 0x80000000u) ? 0xFFFFFFFFu : 0x80000000u);
  return ((unsigned long long)u << 32) | (unsigned)(~idx);
}

__global__ __launch_bounds__(TPB) void ConfusionDropout_52407190946399_kernel(
    const float* __restrict__ x,
    const float* __restrict__ prev,
    const float* __restrict__ W,
    float* __restrict__ out)
{
  const int row  = blockIdx.x;
  const int t    = threadIdx.x;
  const int wave = t >> 6;

  __shared__ unsigned long long s_a0[TPB];
  __shared__ unsigned long long s_a1[TPB];
  __shared__ unsigned s_cnt[2][4];    // double-buffered per-wave counts (binary search)
  __shared__ unsigned s_cnt2[2][4];   // gt / eq counts
  __shared__ unsigned s_scan[TPB];    // rare-path tie scan

  // ---------------- Phase A: top-2 of prev_output[row, :] ----------------
  unsigned long long a0 = 0ull, a1 = 0ull;
  {
    const float* pr = prev + (size_t)row * Cn;
    #pragma unroll
    for (int k = 0; k < 4; ++k) {
      int c = t + k * TPB;
      if (c < Cn) {
        unsigned long long p = pack_pv(pr[c], (unsigned)c);
        if (p > a0)      { a1 = a0; a0 = p; }
        else if (p > a1) { a1 = p; }
      }
    }
  }
  s_a0[t] = a0; s_a1[t] = a1;
  __syncthreads();
  for (int s = TPB / 2; s > 0; s >>= 1) {
    if (t < s) {
      unsigned long long b0 = s_a0[t + s], b1 = s_a1[t + s];
      unsigned long long c0 = s_a0[t],     c1 = s_a1[t];
      unsigned long long n0, n1;
      if (b0 > c0) { n0 = b0; n1 = (c0 > b1) ? c0 : b1; }
      else         { n0 = c0; n1 = (b0 > c1) ? b0 : c1; }
      s_a0[t] = n0; s_a1[t] = n1;
    }
    __syncthreads();
  }
  const unsigned i0 = ~(unsigned)(s_a0[0] & 0xFFFFFFFFull);
  const unsigned i1 = ~(unsigned)(s_a1[0] & 0xFFFFFFFFull);

  // ---------------- Phase B: scores -> u32 keys (order-isomorphic) ----------------
  // Thread t owns channels [t*16, t*16+16). score = |x * (W[i0] - W[i1])|, exact IEEE.
  const float* xr = x + (size_t)row * Dn;
  const float* w0 = W + (size_t)i0 * Dn;
  const float* w1 = W + (size_t)i1 * Dn;

  float    xv[16];
  unsigned key[16];
  #pragma unroll
  for (int j = 0; j < 4; ++j) {
    const int d4 = t * 16 + j * 4;
    float4 xx = *reinterpret_cast<const float4*>(xr + d4);
    float4 aa = *reinterpret_cast<const float4*>(w0 + d4);
    float4 bb = *reinterpret_cast<const float4*>(w1 + d4);
    xv[j*4+0] = xx.x; xv[j*4+1] = xx.y; xv[j*4+2] = xx.z; xv[j*4+3] = xx.w;
    key[j*4+0] = __float_as_uint(xx.x * (aa.x - bb.x)) & 0x7FFFFFFFu;
    key[j*4+1] = __float_as_uint(xx.y * (aa.y - bb.y)) & 0x7FFFFFFFu;
    key[j*4+2] = __float_as_uint(xx.z * (aa.z - bb.z)) & 0x7FFFFFFFu;
    key[j*4+3] = __float_as_uint(xx.w * (aa.w - bb.w)) & 0x7FFFFFFFu;
  }

  // ---------------- Phase C: exact 1024th-largest key via bitwise binary search ----------------
  // Invariant: count(key >= cur) >= NDROP. Keys are nonneg floats -> bit31 == 0.
  unsigned cur = 0;
  #pragma unroll 1
  for (int bit = 30; bit >= 0; --bit) {
    const unsigned cand = cur | (1u << bit);
    unsigned wc = 0;
    #pragma unroll
    for (int j = 0; j < 16; ++j)
      wc += (unsigned)__popcll(__ballot(key[j] >= cand));
    if ((t & 63) == 0) s_cnt[bit & 1][wave] = wc;
    __syncthreads();
    const unsigned tot = s_cnt[bit & 1][0] + s_cnt[bit & 1][1] +
                         s_cnt[bit & 1][2] + s_cnt[bit & 1][3];
    if (tot >= NDROP) cur = cand;
    // no trailing barrier needed: next iter writes the other slot; slot reuse is
    // separated by the next iteration's barrier.
  }
  const unsigned V = cur;  // 1024th-largest key; count(>=V) >= 1024, count(>V) < 1024

  unsigned wgt = 0, weq = 0;
  #pragma unroll
  for (int j = 0; j < 16; ++j) {
    wgt += (unsigned)__popcll(__ballot(key[j] > V));
    weq += (unsigned)__popcll(__ballot(key[j] == V));
  }
  if ((t & 63) == 0) { s_cnt2[0][wave] = wgt; s_cnt2[1][wave] = weq; }
  __syncthreads();
  const unsigned cnt_gt  = s_cnt2[0][0] + s_cnt2[0][1] + s_cnt2[0][2] + s_cnt2[0][3];
  const unsigned cnt_eq  = s_cnt2[1][0] + s_cnt2[1][1] + s_cnt2[1][2] + s_cnt2[1][3];
  const unsigned need_eq = NDROP - cnt_gt;   // 1 <= need_eq <= cnt_eq

  // ---------------- Phase D: build mask (exact stable tie-break) and store ----------------
  bool drop[16];
  if (need_eq == cnt_eq) {
    // common case: all threshold-equal elements are dropped
    #pragma unroll
    for (int j = 0; j < 16; ++j) drop[j] = (key[j] >= V);
  } else {
    // rare straddling tie: rank equal-key elements in increasing channel order
    unsigned c = 0;
    #pragma unroll
    for (int j = 0; j < 16; ++j) c += (key[j] == V) ? 1u : 0u;
    s_scan[t] = c;
    __syncthreads();
    for (int off = 1; off < TPB; off <<= 1) {
      unsigned add = (t >= off) ? s_scan[t - off] : 0u;
      __syncthreads();
      s_scan[t] += add;
      __syncthreads();
    }
    unsigned run = s_scan[t] - c;   // exclusive prefix of eq-count in channel order
    #pragma unroll
    for (int j = 0; j < 16; ++j) {
      if (key[j] == V) { drop[j] = (run < need_eq); ++run; }
      else             { drop[j] = (key[j] > V); }
    }
  }

  float* orow = out + (size_t)row * Dn + t * 16;
  #pragma unroll
  for (int j = 0; j < 4; ++j) {
    float4 o;
    o.x = drop[j*4+0] ? 0.0f : xv[j*4+0];
    o.y = drop[j*4+1] ? 0.0f : xv[j*4+1];
    o.z = drop[j*4+2] ? 0.0f : xv[j*4+2];
    o.w = drop[j*4+3] ? 0.0f : xv[j*4+3];
    *reinterpret_cast<float4*>(orow + j * 4) = o;
  }
}

extern "C" void kernel_launch(void* const* d_in, const int* in_sizes, int n_in,
                              void* d_out, int out_size, void* d_ws, size_t ws_size,
                              hipStream_t stream) {
  const float* x    = (const float*)d_in[0];
  const float* prev = (const float*)d_in[1];
  const float* W    = (const float*)d_in[2];
  float* out        = (float*)d_out;
  const int Brows   = in_sizes[0] / Dn;   // 16384
  ConfusionDropout_52407190946399_kernel<<<Brows, TPB, 0, stream>>>(x, prev, W, out);
}